// Round 6
// baseline (436.838 us; speedup 1.0000x reference)
//
#include <hip/hip_runtime.h>
#include <hip/hip_bf16.h>
#include <hip/hip_fp16.h>

#define N_NODES 50000
#define N_EDGES 800000
#define IN_CH 64
#define EDGE_DIM 8
#define HIDDEN 128
#define NUM_GRAPHS 256
#define NPASS 4
#define PASS_W ((N_NODES + NPASS - 1) / NPASS)   // 12500
#define QSCALE 256.0f
#define QINV   (1.0f / 256.0f)

typedef __attribute__((ext_vector_type(8))) _Float16 half8;
typedef __attribute__((ext_vector_type(4))) float floatx4;
typedef __attribute__((ext_vector_type(4))) int intx4;

static __device__ __forceinline__ __half2 u2h(int u) {
    union { int i; __half2 h; } cv; cv.i = u; return cv.h;
}
static __device__ __forceinline__ int h2u(__half2 h) {
    union { __half2 h; int i; } cv; cv.h = h; return cv.i;
}
static __device__ __forceinline__ unsigned short h1u(__half h) {
    union { __half h; unsigned short u; } cv; cv.h = h; return cv.u;
}

// ===========================================================================
// CSR build: histogram, scan, then NPASS dst-range RECORD scatter passes.
// Order within a node's edge list is the (nondeterministic) atomic arrival
// order -- harmless, because the gather accumulates in int32 fixed-point,
// which is order-insensitive. This deletes the rank sort and eid entirely.
// ===========================================================================
__global__ __launch_bounds__(256) void hist_kernel(
    const int* __restrict__ dst, int* __restrict__ deg, int E)
{
    int i = blockIdx.x * blockDim.x + threadIdx.x;
    if (i < E) atomicAdd(&deg[dst[i]], 1);
}

__global__ __launch_bounds__(256) void scan1_kernel(
    const int* __restrict__ deg, int* __restrict__ incl,
    int* __restrict__ blockSums, int N)
{
    __shared__ int s[256];
    int b = blockIdx.x, t = threadIdx.x;
    int i0 = b * 512 + 2 * t;
    int a0 = (i0 < N) ? deg[i0] : 0;
    int a1 = (i0 + 1 < N) ? deg[i0 + 1] : 0;
    int ps = a0 + a1;
    s[t] = ps;
    __syncthreads();
    for (int off = 1; off < 256; off <<= 1) {
        int v = (t >= off) ? s[t - off] : 0;
        __syncthreads();
        s[t] += v;
        __syncthreads();
    }
    int exclp = s[t] - ps;
    if (i0 < N)     incl[i0]     = exclp + a0;
    if (i0 + 1 < N) incl[i0 + 1] = exclp + a0 + a1;
    if (t == 255) blockSums[b] = s[255];
}

__global__ __launch_bounds__(128) void scan2_kernel(int* __restrict__ blockSums, int B)
{
    __shared__ int s[128];
    int t = threadIdx.x;
    int v = (t < B) ? blockSums[t] : 0;
    s[t] = v;
    __syncthreads();
    for (int off = 1; off < 128; off <<= 1) {
        int u = (t >= off) ? s[t - off] : 0;
        __syncthreads();
        s[t] += u;
        __syncthreads();
    }
    if (t < B) blockSums[t] = s[t] - v;   // exclusive
}

__global__ __launch_bounds__(256) void scan3_kernel(
    const int* __restrict__ incl, const int* __restrict__ deg,
    const int* __restrict__ blockSums, int* __restrict__ rowptr,
    int* __restrict__ pos, int N)
{
    int i = blockIdx.x * blockDim.x + threadIdx.x;
    if (i >= N) return;
    int v = incl[i] - deg[i] + blockSums[i >> 9];
    rowptr[i] = v;
    pos[i] = v;
}

// One dst-range RECORD scatter pass: writes src_s and fp16 edge records
// directly at their CSR position. ea reads are coalesced (e sequential);
// record writes land in a ~4 MB window (L2-resident), nontemporal.
__global__ __launch_bounds__(256) void scatter_rec_kernel(
    const int* __restrict__ dst, const int* __restrict__ src,
    const float* __restrict__ ea, int* __restrict__ pos,
    int* __restrict__ src_s, __half* __restrict__ ea16, int lo, int E)
{
    int e = blockIdx.x * blockDim.x + threadIdx.x;
    if (e >= E) return;
    int d = dst[e];
    if ((unsigned)(d - lo) >= (unsigned)PASS_W) return;
    int p = atomicAdd(&pos[d], 1);
    __builtin_nontemporal_store(src[e], &src_s[p]);
    const float4* q = (const float4*)(ea + (size_t)e * EDGE_DIM);
    float4 a = q[0], b = q[1];
    intx4 r;
    r.x = h2u(__floats2half2_rn(a.x, a.y));
    r.y = h2u(__floats2half2_rn(a.z, a.w));
    r.z = h2u(__floats2half2_rn(b.x, b.y));
    r.w = h2u(__floats2half2_rn(b.z, b.w));
    __builtin_nontemporal_store(r, (intx4*)(ea16 + (size_t)p * EDGE_DIM));
}

// x fp32->fp16 AND all three W -> Wt fp16 transposed, one dispatch.
#define XH_ELEMS (N_NODES * IN_CH)
__global__ __launch_bounds__(256) void cvt_all_kernel(
    const float* __restrict__ x, __half* __restrict__ xh,
    const float* __restrict__ W1, const float* __restrict__ W2,
    const float* __restrict__ W3,
    _Float16* __restrict__ Wt1, _Float16* __restrict__ Wt2,
    _Float16* __restrict__ Wt3)
{
    int idx = blockIdx.x * blockDim.x + threadIdx.x;
    if (idx < XH_ELEMS) { xh[idx] = __float2half(x[idx]); return; }
    idx -= XH_ELEMS;
    if (idx < 128 * IN_CH) {
        int n = idx / IN_CH, k = idx - n * IN_CH;
        Wt1[idx] = (_Float16)W1[k * 128 + n];
        return;
    }
    idx -= 128 * IN_CH;
    if (idx < 128 * HIDDEN) {
        int n = idx / HIDDEN, k = idx - n * HIDDEN;
        Wt2[idx] = (_Float16)W2[k * 128 + n];
        return;
    }
    idx -= 128 * HIDDEN;
    if (idx < 128 * HIDDEN) {
        int n = idx / HIDDEN, k = idx - n * HIDDEN;
        Wt3[idx] = (_Float16)W3[k * 128 + n];
    }
}

// ===========================================================================
// Gather-aggregate: 4 waves/block, one node per wave, 8 edges in flight.
// INT32 fixed-point accumulation (scale 2^8) -> edge-order-insensitive,
// bit-deterministic regardless of the atomic scatter's arrival order.
// Self term added in fp32 at the end (full precision).
//   xs[n][j] = h[n][j] + sum_e relu( h[src][j] + (ea@We+be)[j] )
// ===========================================================================
#define BF 8   // edges in flight per wave

__global__ __launch_bounds__(256) void gather_xs128_kernel(
    const __half* __restrict__ h,       // [N,128] fp16
    const int*    __restrict__ src_s,   // [E] CSR order
    const __half* __restrict__ ea16,    // [E,8] fp16 CSR order
    const int*    __restrict__ rowptr,  // [N]
    const int*    __restrict__ deg,     // [N]
    const float*  __restrict__ We,      // [8,128]
    const float*  __restrict__ be,      // [128]
    __half*       __restrict__ xs,      // [N,128] fp16
    int N)
{
    int wave = threadIdx.x >> 6;
    int n    = blockIdx.x * 4 + wave;
    if (n >= N) return;
    int l  = threadIdx.x & 63;  // lane
    int j0 = 2 * l;

    __half2 hw[8];
    #pragma unroll
    for (int k = 0; k < 8; ++k) {
        float2 wv = *(const float2*)&We[k * 128 + j0];
        hw[k] = __floats2half2_rn(wv.x, wv.y);
    }
    float2 bevf = *(const float2*)&be[j0];
    __half2 bev2 = __floats2half2_rn(bevf.x, bevf.y);

    int start = __builtin_amdgcn_readfirstlane(rowptr[n]);
    int dg    = __builtin_amdgcn_readfirstlane(deg[n]);

    float2 hf = __half22float2(*(const __half2*)&h[(size_t)n * 128 + j0]);
    int acci0 = 0, acci1 = 0;          // fixed-point edge sum

    int nb = dg / BF;                  // full batches
    int base = start;
    for (int b = 0; b < nb; ++b, base += BF) {
        int sid[BF];
        #pragma unroll
        for (int t = 0; t < BF; ++t)
            sid[t] = __builtin_amdgcn_readfirstlane(
                __builtin_nontemporal_load(&src_s[base + t]));
        __half2 hraw[BF];              // random 4B/lane loads (cached - hot)
        #pragma unroll
        for (int t = 0; t < BF; ++t)
            hraw[t] = *(const __half2*)&h[(size_t)sid[t] * 128 + j0];
        intx4 eav[BF];                 // uniform streaming loads - nontemporal
        #pragma unroll
        for (int t = 0; t < BF; ++t)
            eav[t] = __builtin_nontemporal_load(
                (const intx4*)&ea16[(size_t)(base + t) * 8]);

        #pragma unroll
        for (int t = 0; t < BF; ++t) {
            __half2 e01 = u2h(eav[t].x), e23 = u2h(eav[t].y);
            __half2 e45 = u2h(eav[t].z), e67 = u2h(eav[t].w);
            __half2 m = __hfma2(__low2half2(e01),  hw[0], bev2);
            m = __hfma2(__high2half2(e01), hw[1], m);
            m = __hfma2(__low2half2(e23),  hw[2], m);
            m = __hfma2(__high2half2(e23), hw[3], m);
            m = __hfma2(__low2half2(e45),  hw[4], m);
            m = __hfma2(__high2half2(e45), hw[5], m);
            m = __hfma2(__low2half2(e67),  hw[6], m);
            m = __hfma2(__high2half2(e67), hw[7], m);
            m = __hadd2(m, hraw[t]);
            float2 mf = __half22float2(m);
            acci0 += (int)((mf.x > 0.0f ? mf.x : 0.0f) * QSCALE);
            acci1 += (int)((mf.y > 0.0f ? mf.y : 0.0f) * QSCALE);
        }
    }
    // tail (< BF edges)
    int end = start + dg;
    for (int idx = base; idx < end; ++idx) {
        int s = __builtin_amdgcn_readfirstlane(src_s[idx]);
        __half2 hr = *(const __half2*)&h[(size_t)s * 128 + j0];
        intx4 ev = __builtin_nontemporal_load((const intx4*)&ea16[(size_t)idx * 8]);
        __half2 e01 = u2h(ev.x), e23 = u2h(ev.y), e45 = u2h(ev.z), e67 = u2h(ev.w);
        __half2 m = __hfma2(__low2half2(e01),  hw[0], bev2);
        m = __hfma2(__high2half2(e01), hw[1], m);
        m = __hfma2(__low2half2(e23),  hw[2], m);
        m = __hfma2(__high2half2(e23), hw[3], m);
        m = __hfma2(__low2half2(e45),  hw[4], m);
        m = __hfma2(__high2half2(e45), hw[5], m);
        m = __hfma2(__low2half2(e67),  hw[6], m);
        m = __hfma2(__high2half2(e67), hw[7], m);
        m = __hadd2(m, hr);
        float2 mf = __half22float2(m);
        acci0 += (int)((mf.x > 0.0f ? mf.x : 0.0f) * QSCALE);
        acci1 += (int)((mf.y > 0.0f ? mf.y : 0.0f) * QSCALE);
    }
    float acc0 = hf.x + (float)acci0 * QINV;
    float acc1 = hf.y + (float)acci1 * QINV;
    __builtin_nontemporal_store(h2u(__floats2half2_rn(acc0, acc1)),
                                (int*)&xs[(size_t)n * 128 + j0]);
}

// D=64: 4 waves/block, one node per wave, 1 feature/lane. Int accumulation.
__global__ __launch_bounds__(256) void gather_xs64_kernel(
    const __half* __restrict__ h,       // [N,64] fp16
    const int*    __restrict__ src_s,
    const __half* __restrict__ ea16,    // [E,8] fp16
    const int*    __restrict__ rowptr,
    const int*    __restrict__ deg,
    const float*  __restrict__ We,      // [8,64]
    const float*  __restrict__ be,      // [64]
    __half*       __restrict__ xs,      // [N,64] fp16
    int N)
{
    int wave = threadIdx.x >> 6;
    int n    = blockIdx.x * 4 + wave;
    if (n >= N) return;
    int j = threadIdx.x & 63;

    __half2 w2[4];
    #pragma unroll
    for (int p = 0; p < 4; ++p)
        w2[p] = __floats2half2_rn(We[(2 * p) * 64 + j], We[(2 * p + 1) * 64 + j]);
    float bej = be[j];

    int start = __builtin_amdgcn_readfirstlane(rowptr[n]);
    int dg    = __builtin_amdgcn_readfirstlane(deg[n]);

    float selff = __half2float(h[(size_t)n * 64 + j]);   // self term
    int acci = 0;

    int nb = dg / BF;
    int base = start;
    for (int b = 0; b < nb; ++b, base += BF) {
        int sid[BF];
        #pragma unroll
        for (int t = 0; t < BF; ++t)
            sid[t] = __builtin_amdgcn_readfirstlane(
                __builtin_nontemporal_load(&src_s[base + t]));
        __half hraw[BF];
        #pragma unroll
        for (int t = 0; t < BF; ++t)
            hraw[t] = h[(size_t)sid[t] * 64 + j];
        intx4 eav[BF];
        #pragma unroll
        for (int t = 0; t < BF; ++t)
            eav[t] = __builtin_nontemporal_load(
                (const intx4*)&ea16[(size_t)(base + t) * 8]);

        #pragma unroll
        for (int t = 0; t < BF; ++t) {
            __half2 d = __hmul2(u2h(eav[t].x), w2[0]);
            d = __hfma2(u2h(eav[t].y), w2[1], d);
            d = __hfma2(u2h(eav[t].z), w2[2], d);
            d = __hfma2(u2h(eav[t].w), w2[3], d);
            float proj = __half2float(__low2half(d)) + __half2float(__high2half(d));
            float m = __half2float(hraw[t]) + proj + bej;
            acci += (int)((m > 0.0f ? m : 0.0f) * QSCALE);
        }
    }
    int end = start + dg;
    for (int idx = base; idx < end; ++idx) {
        int s = __builtin_amdgcn_readfirstlane(src_s[idx]);
        __half hr = h[(size_t)s * 64 + j];
        intx4 ev = __builtin_nontemporal_load((const intx4*)&ea16[(size_t)idx * 8]);
        __half2 d = __hmul2(u2h(ev.x), w2[0]);
        d = __hfma2(u2h(ev.y), w2[1], d);
        d = __hfma2(u2h(ev.z), w2[2], d);
        d = __hfma2(u2h(ev.w), w2[3], d);
        float proj = __half2float(__low2half(d)) + __half2float(__high2half(d));
        float m = __half2float(hr) + proj + bej;
        acci += (int)((m > 0.0f ? m : 0.0f) * QSCALE);
    }
    float acc = selff + (float)acci * QINV;
    __builtin_nontemporal_store(h1u(__float2half(acc)),
                                (unsigned short*)&xs[(size_t)n * 64 + j]);
}

// ===========================================================================
// Node GEMM on matrix cores: out = relu(xs @ W + b), fp16 in/out, fp32 acc.
// ===========================================================================
template<int K>
__global__ __launch_bounds__(256) void node_mfma_kernel(
    const _Float16* __restrict__ xs,   // [N,K] fp16
    const _Float16* __restrict__ Wt,   // [128][K] fp16 (W transposed)
    const float*    __restrict__ b,    // [128]
    _Float16*       __restrict__ out,  // [N,128] fp16
    int N)
{
    int wave  = threadIdx.x >> 6;             // 0..3
    int lane  = threadIdx.x & 63;
    int row16 = lane & 15;
    int quad  = lane >> 4;
    int m0    = (blockIdx.x * 4 + wave) * 32;

    int nA = m0 + row16;        if (nA >= N) nA = N - 1;
    int nB = m0 + 16 + row16;   if (nB >= N) nB = N - 1;

    floatx4 accA[8], accB[8];
    #pragma unroll
    for (int t = 0; t < 8; ++t) { accA[t] = (floatx4)(0.0f); accB[t] = (floatx4)(0.0f); }

    #pragma unroll
    for (int kc = 0; kc < K; kc += 32) {
        half8 a0 = __builtin_nontemporal_load((const half8*)&xs[(size_t)nA * K + kc + quad * 8]);
        half8 a1 = __builtin_nontemporal_load((const half8*)&xs[(size_t)nB * K + kc + quad * 8]);
        #pragma unroll
        for (int t = 0; t < 8; ++t) {
            half8 bf = *(const half8*)&Wt[(size_t)(t * 16 + row16) * K + kc + quad * 8];
            accA[t] = __builtin_amdgcn_mfma_f32_16x16x32_f16(a0, bf, accA[t], 0, 0, 0);
            accB[t] = __builtin_amdgcn_mfma_f32_16x16x32_f16(a1, bf, accB[t], 0, 0, 0);
        }
    }

    #pragma unroll
    for (int t = 0; t < 8; ++t) {
        int col = t * 16 + row16;
        float bj = b[col];
        #pragma unroll
        for (int r = 0; r < 4; ++r) {
            int nodeA = m0 + quad * 4 + r;
            if (nodeA < N) {
                float v = accA[t][r] + bj;
                out[(size_t)nodeA * 128 + col] = (_Float16)(v > 0.0f ? v : 0.0f);
            }
            int nodeB = m0 + 16 + quad * 4 + r;
            if (nodeB < N) {
                float v = accB[t][r] + bj;
                out[(size_t)nodeB * 128 + col] = (_Float16)(v > 0.0f ? v : 0.0f);
            }
        }
    }
}

// ===========================================================================
// Pool: one block per graph; 256 threads = 4 node-streams x 64 feature-pairs.
// ===========================================================================
__global__ __launch_bounds__(256) void pool_kernel(
    const __half* __restrict__ h,      // [N, 128] fp16
    const int*    __restrict__ batch,  // [N] sorted
    float*        __restrict__ out,    // [G, 128]
    int N)
{
    __shared__ int s_lo, s_hi;
    __shared__ float part[4][128];
    int g  = blockIdx.x;
    int t  = threadIdx.x;
    int fp = t & 63;        // feature pair: features 2fp, 2fp+1
    int r  = t >> 6;        // node stream 0..3

    if (t == 0) {
        int lo = 0, hi = N;
        while (lo < hi) { int m = (lo + hi) >> 1; if (batch[m] < g) lo = m + 1; else hi = m; }
        s_lo = lo;
        int lo2 = lo, hi2 = N;
        while (lo2 < hi2) { int m = (lo2 + hi2) >> 1; if (batch[m] < g + 1) lo2 = m + 1; else hi2 = m; }
        s_hi = lo2;
    }
    __syncthreads();

    int lo = s_lo, hi = s_hi;
    float a0 = 0.0f, a1 = 0.0f;
    for (int n = lo + r; n < hi; n += 4) {
        float2 f = __half22float2(*(const __half2*)&h[(size_t)n * 128 + 2 * fp]);
        a0 += f.x; a1 += f.y;
    }
    part[r][2 * fp]     = a0;
    part[r][2 * fp + 1] = a1;
    __syncthreads();

    if (r == 0) {
        float s0 = part[0][2 * fp] + part[1][2 * fp] + part[2][2 * fp] + part[3][2 * fp];
        float s1 = part[0][2 * fp + 1] + part[1][2 * fp + 1] + part[2][2 * fp + 1] + part[3][2 * fp + 1];
        float c = (float)(hi - lo);
        float d = c > 1.0f ? c : 1.0f;
        out[g * HIDDEN + 2 * fp]     = s0 / d;
        out[g * HIDDEN + 2 * fp + 1] = s1 / d;
    }
}

// ===========================================================================
extern "C" void kernel_launch(void* const* d_in, const int* in_sizes, int n_in,
                              void* d_out, int out_size, void* d_ws, size_t ws_size,
                              hipStream_t stream)
{
    const float* x   = (const float*)d_in[0];      // [N, 64]
    const int*   ei  = (const int*)d_in[1];        // [2, E]
    const float* ea  = (const float*)d_in[2];      // [E, 8]
    const int*   bat = (const int*)d_in[3];        // [N]
    const float* W1  = (const float*)d_in[4];
    const float* b1  = (const float*)d_in[5];
    const float* We1 = (const float*)d_in[6];
    const float* be1 = (const float*)d_in[7];
    const float* W2  = (const float*)d_in[8];
    const float* b2  = (const float*)d_in[9];
    const float* We2 = (const float*)d_in[10];
    const float* be2 = (const float*)d_in[11];
    const float* W3  = (const float*)d_in[12];
    const float* b3  = (const float*)d_in[13];
    const float* We3 = (const float*)d_in[14];
    const float* be3 = (const float*)d_in[15];
    float* out = (float*)d_out;

    const int* src = ei;
    const int* dst = ei + N_EDGES;

    // ---------------- workspace layout (eid slot retained, unused) --------
    int* deg       = (int*)d_ws;                             // [N]
    int* rowptr    = deg + N_NODES;                          // [N]
    int* pos       = rowptr + N_NODES;                       // [N]
    int* eid       = pos + N_NODES;                          // [E] (unused)
    int* src_s     = eid + N_EDGES;                          // [E]
    int* blockSums = src_s + N_EDGES;                        // [128]
    __half* ea16   = (__half*)(blockSums + 128);             // [E, 8] fp16
    __half* xs     = ea16 + (size_t)N_EDGES * EDGE_DIM;      // [N,128] fp16
    __half* xh     = xs + (size_t)N_NODES * HIDDEN;          // [N, 64] fp16
    __half* h1h    = xh + (size_t)N_NODES * IN_CH;           // [N, 128] fp16
    __half* h2h    = h1h + (size_t)N_NODES * HIDDEN;         // [N, 128] fp16
    _Float16* Wt1  = (_Float16*)(h2h + (size_t)N_NODES * HIDDEN); // [128,64]
    _Float16* Wt2  = Wt1 + 128 * IN_CH;                      // [128,128]
    _Float16* Wt3  = Wt2 + 128 * HIDDEN;                     // [128,128]
    (void)eid;

    const int BLK = 256;
    const int NB_E = (N_EDGES + BLK - 1) / BLK;
    const int NB_N = (N_NODES + BLK - 1) / BLK;
    const int SCAN_B = (N_NODES + 511) / 512;    // 98
    const int MFMA_B = (N_NODES + 127) / 128;    // 391
    const int WAVE4_B = (N_NODES + 3) / 4;       // 12500 (4 waves/block, 1 node/wave)
    const int CVT_ELEMS = XH_ELEMS + 128 * IN_CH + 2 * 128 * HIDDEN;

    // ---------------- CSR build (sortless, record scatter) ----------------
    (void)hipMemsetAsync(deg, 0, N_NODES * sizeof(int), stream);
    hist_kernel<<<NB_E, BLK, 0, stream>>>(dst, deg, N_EDGES);
    scan1_kernel<<<SCAN_B, 256, 0, stream>>>(deg, pos, blockSums, N_NODES);
    scan2_kernel<<<1, 128, 0, stream>>>(blockSums, SCAN_B);
    scan3_kernel<<<NB_N, BLK, 0, stream>>>(pos, deg, blockSums, rowptr, pos, N_NODES);
    for (int pass = 0; pass < NPASS; ++pass) {
        scatter_rec_kernel<<<NB_E, BLK, 0, stream>>>(
            dst, src, ea, pos, src_s, ea16, pass * PASS_W, N_EDGES);
    }
    cvt_all_kernel<<<(CVT_ELEMS + BLK - 1) / BLK, BLK, 0, stream>>>(
        x, xh, W1, W2, W3, Wt1, Wt2, Wt3);

    // ---------------- layer 1 (64 -> 128) ----------------
    gather_xs64_kernel<<<WAVE4_B, BLK, 0, stream>>>(
        xh, src_s, ea16, rowptr, deg, We1, be1, xs, N_NODES);
    node_mfma_kernel<IN_CH><<<MFMA_B, 256, 0, stream>>>(
        (const _Float16*)xs, Wt1, b1, (_Float16*)h1h, N_NODES);

    // ---------------- layer 2 (128 -> 128) ----------------
    gather_xs128_kernel<<<WAVE4_B, BLK, 0, stream>>>(
        h1h, src_s, ea16, rowptr, deg, We2, be2, xs, N_NODES);
    node_mfma_kernel<HIDDEN><<<MFMA_B, 256, 0, stream>>>(
        (const _Float16*)xs, Wt2, b2, (_Float16*)h2h, N_NODES);

    // ---------------- layer 3 (128 -> 128) ----------------
    gather_xs128_kernel<<<WAVE4_B, BLK, 0, stream>>>(
        h2h, src_s, ea16, rowptr, deg, We3, be3, xs, N_NODES);
    node_mfma_kernel<HIDDEN><<<MFMA_B, 256, 0, stream>>>(
        (const _Float16*)xs, Wt3, b3, (_Float16*)h1h, N_NODES);

    // ---------------- global mean pool (256 threads: 4 streams x 64 pairs) --
    pool_kernel<<<NUM_GRAPHS, 256, 0, stream>>>(h1h, bat, out, N_NODES);
}

// Round 7
// 419.600 us; speedup vs baseline: 1.0411x; 1.0411x over previous
//
#include <hip/hip_runtime.h>
#include <hip/hip_bf16.h>
#include <hip/hip_fp16.h>

#define N_NODES 50000
#define N_EDGES 800000
#define IN_CH 64
#define EDGE_DIM 8
#define HIDDEN 128
#define NUM_GRAPHS 256
#define NPASS 2
#define PASS_W ((N_NODES + NPASS - 1) / NPASS)   // 25000
#define QSCALE 256.0f
#define QINV   (1.0f / 256.0f)

typedef __attribute__((ext_vector_type(8))) _Float16 half8;
typedef __attribute__((ext_vector_type(4))) float floatx4;
typedef __attribute__((ext_vector_type(2))) float floatx2;
typedef __attribute__((ext_vector_type(4))) int intx4;

static __device__ __forceinline__ __half2 u2h(int u) {
    union { int i; __half2 h; } cv; cv.i = u; return cv.h;
}
static __device__ __forceinline__ int h2u(__half2 h) {
    union { __half2 h; int i; } cv; cv.h = h; return cv.i;
}
static __device__ __forceinline__ unsigned short h1u(__half h) {
    union { __half h; unsigned short u; } cv; cv.h = h; return cv.u;
}
// fp8 e4m3 helpers (gfx950 OCP)
static __device__ __forceinline__ unsigned char f32_to_fp8(float v) {
    int pk = __builtin_amdgcn_cvt_pk_fp8_f32(v, v, 0, false);
    return (unsigned char)(pk & 0xff);
}

// ===========================================================================
// CSR build: histogram, scan, then NPASS dst-range RECORD scatter passes.
// Edge order within a node = atomic arrival order (nondeterministic) --
// harmless: gathers accumulate in int32 fixed point (order-insensitive).
// ===========================================================================
__global__ __launch_bounds__(256) void hist_kernel(
    const int* __restrict__ dst, int* __restrict__ deg, int E)
{
    int i = blockIdx.x * blockDim.x + threadIdx.x;
    if (i < E) atomicAdd(&deg[dst[i]], 1);
}

__global__ __launch_bounds__(256) void scan1_kernel(
    const int* __restrict__ deg, int* __restrict__ incl,
    int* __restrict__ blockSums, int N)
{
    __shared__ int s[256];
    int b = blockIdx.x, t = threadIdx.x;
    int i0 = b * 512 + 2 * t;
    int a0 = (i0 < N) ? deg[i0] : 0;
    int a1 = (i0 + 1 < N) ? deg[i0 + 1] : 0;
    int ps = a0 + a1;
    s[t] = ps;
    __syncthreads();
    for (int off = 1; off < 256; off <<= 1) {
        int v = (t >= off) ? s[t - off] : 0;
        __syncthreads();
        s[t] += v;
        __syncthreads();
    }
    int exclp = s[t] - ps;
    if (i0 < N)     incl[i0]     = exclp + a0;
    if (i0 + 1 < N) incl[i0 + 1] = exclp + a0 + a1;
    if (t == 255) blockSums[b] = s[255];
}

__global__ __launch_bounds__(128) void scan2_kernel(int* __restrict__ blockSums, int B)
{
    __shared__ int s[128];
    int t = threadIdx.x;
    int v = (t < B) ? blockSums[t] : 0;
    s[t] = v;
    __syncthreads();
    for (int off = 1; off < 128; off <<= 1) {
        int u = (t >= off) ? s[t - off] : 0;
        __syncthreads();
        s[t] += u;
        __syncthreads();
    }
    if (t < B) blockSums[t] = s[t] - v;   // exclusive
}

__global__ __launch_bounds__(256) void scan3_kernel(
    const int* __restrict__ incl, const int* __restrict__ deg,
    const int* __restrict__ blockSums, int* __restrict__ rowptr,
    int* __restrict__ pos, int N)
{
    int i = blockIdx.x * blockDim.x + threadIdx.x;
    if (i >= N) return;
    int v = incl[i] - deg[i] + blockSums[i >> 9];
    rowptr[i] = v;
    pos[i] = v;
}

// One dst-range RECORD scatter pass (writes src_s + fp16 edge record).
__global__ __launch_bounds__(256) void scatter_rec_kernel(
    const int* __restrict__ dst, const int* __restrict__ src,
    const float* __restrict__ ea, int* __restrict__ pos,
    int* __restrict__ src_s, __half* __restrict__ ea16, int lo, int E)
{
    int e = blockIdx.x * blockDim.x + threadIdx.x;
    if (e >= E) return;
    int d = dst[e];
    if ((unsigned)(d - lo) >= (unsigned)PASS_W) return;
    int p = atomicAdd(&pos[d], 1);
    __builtin_nontemporal_store(src[e], &src_s[p]);
    const float4* q = (const float4*)(ea + (size_t)e * EDGE_DIM);
    float4 a = q[0], b = q[1];
    intx4 r;
    r.x = h2u(__floats2half2_rn(a.x, a.y));
    r.y = h2u(__floats2half2_rn(a.z, a.w));
    r.z = h2u(__floats2half2_rn(b.x, b.y));
    r.w = h2u(__floats2half2_rn(b.z, b.w));
    __builtin_nontemporal_store(r, (intx4*)(ea16 + (size_t)p * EDGE_DIM));
}

// x fp32 -> fp8 gather table AND all three W -> Wt fp16 transposed.
#define XH_ELEMS (N_NODES * IN_CH)
__global__ __launch_bounds__(256) void cvt_all_kernel(
    const float* __restrict__ x, unsigned char* __restrict__ xh8,
    const float* __restrict__ W1, const float* __restrict__ W2,
    const float* __restrict__ W3,
    _Float16* __restrict__ Wt1, _Float16* __restrict__ Wt2,
    _Float16* __restrict__ Wt3)
{
    int idx = blockIdx.x * blockDim.x + threadIdx.x;
    if (idx < XH_ELEMS) { xh8[idx] = f32_to_fp8(x[idx]); return; }
    idx -= XH_ELEMS;
    if (idx < 128 * IN_CH) {
        int n = idx / IN_CH, k = idx - n * IN_CH;
        Wt1[idx] = (_Float16)W1[k * 128 + n];
        return;
    }
    idx -= 128 * IN_CH;
    if (idx < 128 * HIDDEN) {
        int n = idx / HIDDEN, k = idx - n * HIDDEN;
        Wt2[idx] = (_Float16)W2[k * 128 + n];
        return;
    }
    idx -= 128 * HIDDEN;
    if (idx < 128 * HIDDEN) {
        int n = idx / HIDDEN, k = idx - n * HIDDEN;
        Wt3[idx] = (_Float16)W3[k * 128 + n];
    }
}

// ===========================================================================
// Gather-aggregate over FP8 h-table: 4 waves/block, one node/wave, 8 edges in
// flight. h rows are 128 B fp8 (2 lines/row): halves cross-XCD L2 duplication
// and line count vs fp16. INT32 fixed-point acc -> order-insensitive.
//   xs[n][j] = h[n][j] + sum_e relu( h[src][j] + (ea@We+be)[j] )   (fp16 out)
// ===========================================================================
#define BF 8   // edges in flight per wave

__global__ __launch_bounds__(256) void gather_xs128_kernel(
    const unsigned char* __restrict__ h8,   // [N,128] fp8
    const int*    __restrict__ src_s,       // [E] CSR order
    const __half* __restrict__ ea16,        // [E,8] fp16 CSR order
    const int*    __restrict__ rowptr,      // [N]
    const int*    __restrict__ deg,         // [N]
    const float*  __restrict__ We,          // [8,128]
    const float*  __restrict__ be,          // [128]
    __half*       __restrict__ xs,          // [N,128] fp16
    int N)
{
    int wave = threadIdx.x >> 6;
    int n    = blockIdx.x * 4 + wave;
    if (n >= N) return;
    int l  = threadIdx.x & 63;  // lane
    int j0 = 2 * l;

    __half2 hw[8];
    #pragma unroll
    for (int k = 0; k < 8; ++k) {
        float2 wv = *(const float2*)&We[k * 128 + j0];
        hw[k] = __floats2half2_rn(wv.x, wv.y);
    }
    float2 bevf = *(const float2*)&be[j0];
    __half2 bev2 = __floats2half2_rn(bevf.x, bevf.y);

    int start = __builtin_amdgcn_readfirstlane(rowptr[n]);
    int dg    = __builtin_amdgcn_readfirstlane(deg[n]);

    unsigned short selfraw = *(const unsigned short*)&h8[(size_t)n * 128 + j0];
    floatx2 hf = __builtin_amdgcn_cvt_pk_f32_fp8((int)selfraw, false);
    int acci0 = 0, acci1 = 0;          // fixed-point edge sum

    int nb = dg / BF;                  // full batches
    int base = start;
    for (int b = 0; b < nb; ++b, base += BF) {
        int sid[BF];
        #pragma unroll
        for (int t = 0; t < BF; ++t)
            sid[t] = __builtin_amdgcn_readfirstlane(
                __builtin_nontemporal_load(&src_s[base + t]));
        unsigned short hraw[BF];       // random 2B/lane loads (cached - hot)
        #pragma unroll
        for (int t = 0; t < BF; ++t)
            hraw[t] = *(const unsigned short*)&h8[(size_t)sid[t] * 128 + j0];
        intx4 eav[BF];                 // uniform streaming loads - nontemporal
        #pragma unroll
        for (int t = 0; t < BF; ++t)
            eav[t] = __builtin_nontemporal_load(
                (const intx4*)&ea16[(size_t)(base + t) * 8]);

        #pragma unroll
        for (int t = 0; t < BF; ++t) {
            __half2 e01 = u2h(eav[t].x), e23 = u2h(eav[t].y);
            __half2 e45 = u2h(eav[t].z), e67 = u2h(eav[t].w);
            __half2 m = __hfma2(__low2half2(e01),  hw[0], bev2);
            m = __hfma2(__high2half2(e01), hw[1], m);
            m = __hfma2(__low2half2(e23),  hw[2], m);
            m = __hfma2(__high2half2(e23), hw[3], m);
            m = __hfma2(__low2half2(e45),  hw[4], m);
            m = __hfma2(__high2half2(e45), hw[5], m);
            m = __hfma2(__low2half2(e67),  hw[6], m);
            m = __hfma2(__high2half2(e67), hw[7], m);
            floatx2 hs = __builtin_amdgcn_cvt_pk_f32_fp8((int)hraw[t], false);
            float m0 = __half2float(__low2half(m))  + hs.x;
            float m1 = __half2float(__high2half(m)) + hs.y;
            acci0 += (int)((m0 > 0.0f ? m0 : 0.0f) * QSCALE);
            acci1 += (int)((m1 > 0.0f ? m1 : 0.0f) * QSCALE);
        }
    }
    // tail (< BF edges)
    int end = start + dg;
    for (int idx = base; idx < end; ++idx) {
        int s = __builtin_amdgcn_readfirstlane(src_s[idx]);
        unsigned short hr = *(const unsigned short*)&h8[(size_t)s * 128 + j0];
        intx4 ev = __builtin_nontemporal_load((const intx4*)&ea16[(size_t)idx * 8]);
        __half2 e01 = u2h(ev.x), e23 = u2h(ev.y), e45 = u2h(ev.z), e67 = u2h(ev.w);
        __half2 m = __hfma2(__low2half2(e01),  hw[0], bev2);
        m = __hfma2(__high2half2(e01), hw[1], m);
        m = __hfma2(__low2half2(e23),  hw[2], m);
        m = __hfma2(__high2half2(e23), hw[3], m);
        m = __hfma2(__low2half2(e45),  hw[4], m);
        m = __hfma2(__high2half2(e45), hw[5], m);
        m = __hfma2(__low2half2(e67),  hw[6], m);
        m = __hfma2(__high2half2(e67), hw[7], m);
        floatx2 hs = __builtin_amdgcn_cvt_pk_f32_fp8((int)hr, false);
        float m0 = __half2float(__low2half(m))  + hs.x;
        float m1 = __half2float(__high2half(m)) + hs.y;
        acci0 += (int)((m0 > 0.0f ? m0 : 0.0f) * QSCALE);
        acci1 += (int)((m1 > 0.0f ? m1 : 0.0f) * QSCALE);
    }
    float acc0 = hf.x + (float)acci0 * QINV;
    float acc1 = hf.y + (float)acci1 * QINV;
    __builtin_nontemporal_store(h2u(__floats2half2_rn(acc0, acc1)),
                                (int*)&xs[(size_t)n * 128 + j0]);
}

// D=64 over fp8 x-table (64 B rows -> 1 line/row, 3.2 MB table: L2-resident).
__global__ __launch_bounds__(256) void gather_xs64_kernel(
    const unsigned char* __restrict__ h8,   // [N,64] fp8
    const int*    __restrict__ src_s,
    const __half* __restrict__ ea16,        // [E,8] fp16
    const int*    __restrict__ rowptr,
    const int*    __restrict__ deg,
    const float*  __restrict__ We,          // [8,64]
    const float*  __restrict__ be,          // [64]
    __half*       __restrict__ xs,          // [N,64] fp16
    int N)
{
    int wave = threadIdx.x >> 6;
    int n    = blockIdx.x * 4 + wave;
    if (n >= N) return;
    int j = threadIdx.x & 63;

    __half2 w2[4];
    #pragma unroll
    for (int p = 0; p < 4; ++p)
        w2[p] = __floats2half2_rn(We[(2 * p) * 64 + j], We[(2 * p + 1) * 64 + j]);
    float bej = be[j];

    int start = __builtin_amdgcn_readfirstlane(rowptr[n]);
    int dg    = __builtin_amdgcn_readfirstlane(deg[n]);

    float selff = __builtin_amdgcn_cvt_f32_fp8((int)h8[(size_t)n * 64 + j], 0);
    int acci = 0;

    int nb = dg / BF;
    int base = start;
    for (int b = 0; b < nb; ++b, base += BF) {
        int sid[BF];
        #pragma unroll
        for (int t = 0; t < BF; ++t)
            sid[t] = __builtin_amdgcn_readfirstlane(
                __builtin_nontemporal_load(&src_s[base + t]));
        unsigned char hraw[BF];
        #pragma unroll
        for (int t = 0; t < BF; ++t)
            hraw[t] = h8[(size_t)sid[t] * 64 + j];
        intx4 eav[BF];
        #pragma unroll
        for (int t = 0; t < BF; ++t)
            eav[t] = __builtin_nontemporal_load(
                (const intx4*)&ea16[(size_t)(base + t) * 8]);

        #pragma unroll
        for (int t = 0; t < BF; ++t) {
            __half2 d = __hmul2(u2h(eav[t].x), w2[0]);
            d = __hfma2(u2h(eav[t].y), w2[1], d);
            d = __hfma2(u2h(eav[t].z), w2[2], d);
            d = __hfma2(u2h(eav[t].w), w2[3], d);
            float proj = __half2float(__low2half(d)) + __half2float(__high2half(d));
            float hrf = __builtin_amdgcn_cvt_f32_fp8((int)hraw[t], 0);
            float m = hrf + proj + bej;
            acci += (int)((m > 0.0f ? m : 0.0f) * QSCALE);
        }
    }
    int end = start + dg;
    for (int idx = base; idx < end; ++idx) {
        int s = __builtin_amdgcn_readfirstlane(src_s[idx]);
        float hrf = __builtin_amdgcn_cvt_f32_fp8((int)h8[(size_t)s * 64 + j], 0);
        intx4 ev = __builtin_nontemporal_load((const intx4*)&ea16[(size_t)idx * 8]);
        __half2 d = __hmul2(u2h(ev.x), w2[0]);
        d = __hfma2(u2h(ev.y), w2[1], d);
        d = __hfma2(u2h(ev.z), w2[2], d);
        d = __hfma2(u2h(ev.w), w2[3], d);
        float proj = __half2float(__low2half(d)) + __half2float(__high2half(d));
        float m = hrf + proj + bej;
        acci += (int)((m > 0.0f ? m : 0.0f) * QSCALE);
    }
    float acc = selff + (float)acci * QINV;
    __builtin_nontemporal_store(h1u(__float2half(acc)),
                                (unsigned short*)&xs[(size_t)n * 64 + j]);
}

// ===========================================================================
// Node GEMM on matrix cores: out = relu(xs @ W + b), fp16 in, fp32 acc.
// OUT8: writes the fp8 gather table for the next layer (layers 1-2);
// else fp16 (layer 3, feeds pool).
// ===========================================================================
template<int K, bool OUT8>
__global__ __launch_bounds__(256) void node_mfma_kernel(
    const _Float16* __restrict__ xs,   // [N,K] fp16
    const _Float16* __restrict__ Wt,   // [128][K] fp16 (W transposed)
    const float*    __restrict__ b,    // [128]
    _Float16*       __restrict__ out16,   // [N,128] fp16 (if !OUT8)
    unsigned char*  __restrict__ out8,    // [N,128] fp8  (if OUT8)
    int N)
{
    int wave  = threadIdx.x >> 6;             // 0..3
    int lane  = threadIdx.x & 63;
    int row16 = lane & 15;
    int quad  = lane >> 4;
    int m0    = (blockIdx.x * 4 + wave) * 32;

    int nA = m0 + row16;        if (nA >= N) nA = N - 1;
    int nB = m0 + 16 + row16;   if (nB >= N) nB = N - 1;

    floatx4 accA[8], accB[8];
    #pragma unroll
    for (int t = 0; t < 8; ++t) { accA[t] = (floatx4)(0.0f); accB[t] = (floatx4)(0.0f); }

    #pragma unroll
    for (int kc = 0; kc < K; kc += 32) {
        half8 a0 = __builtin_nontemporal_load((const half8*)&xs[(size_t)nA * K + kc + quad * 8]);
        half8 a1 = __builtin_nontemporal_load((const half8*)&xs[(size_t)nB * K + kc + quad * 8]);
        #pragma unroll
        for (int t = 0; t < 8; ++t) {
            half8 bf = *(const half8*)&Wt[(size_t)(t * 16 + row16) * K + kc + quad * 8];
            accA[t] = __builtin_amdgcn_mfma_f32_16x16x32_f16(a0, bf, accA[t], 0, 0, 0);
            accB[t] = __builtin_amdgcn_mfma_f32_16x16x32_f16(a1, bf, accB[t], 0, 0, 0);
        }
    }

    #pragma unroll
    for (int t = 0; t < 8; ++t) {
        int col = t * 16 + row16;
        float bj = b[col];
        #pragma unroll
        for (int r = 0; r < 4; ++r) {
            int nodeA = m0 + quad * 4 + r;
            if (nodeA < N) {
                float v = accA[t][r] + bj;
                v = v > 0.0f ? v : 0.0f;
                if (OUT8) out8[(size_t)nodeA * 128 + col] = f32_to_fp8(v);
                else      out16[(size_t)nodeA * 128 + col] = (_Float16)v;
            }
            int nodeB = m0 + 16 + quad * 4 + r;
            if (nodeB < N) {
                float v = accB[t][r] + bj;
                v = v > 0.0f ? v : 0.0f;
                if (OUT8) out8[(size_t)nodeB * 128 + col] = f32_to_fp8(v);
                else      out16[(size_t)nodeB * 128 + col] = (_Float16)v;
            }
        }
    }
}

// ===========================================================================
// Pool: one block per graph; 256 threads = 4 node-streams x 64 feature-pairs.
// ===========================================================================
__global__ __launch_bounds__(256) void pool_kernel(
    const __half* __restrict__ h,      // [N, 128] fp16
    const int*    __restrict__ batch,  // [N] sorted
    float*        __restrict__ out,    // [G, 128]
    int N)
{
    __shared__ int s_lo, s_hi;
    __shared__ float part[4][128];
    int g  = blockIdx.x;
    int t  = threadIdx.x;
    int fp = t & 63;        // feature pair: features 2fp, 2fp+1
    int r  = t >> 6;        // node stream 0..3

    if (t == 0) {
        int lo = 0, hi = N;
        while (lo < hi) { int m = (lo + hi) >> 1; if (batch[m] < g) lo = m + 1; else hi = m; }
        s_lo = lo;
        int lo2 = lo, hi2 = N;
        while (lo2 < hi2) { int m = (lo2 + hi2) >> 1; if (batch[m] < g + 1) lo2 = m + 1; else hi2 = m; }
        s_hi = lo2;
    }
    __syncthreads();

    int lo = s_lo, hi = s_hi;
    float a0 = 0.0f, a1 = 0.0f;
    for (int n = lo + r; n < hi; n += 4) {
        float2 f = __half22float2(*(const __half2*)&h[(size_t)n * 128 + 2 * fp]);
        a0 += f.x; a1 += f.y;
    }
    part[r][2 * fp]     = a0;
    part[r][2 * fp + 1] = a1;
    __syncthreads();

    if (r == 0) {
        float s0 = part[0][2 * fp] + part[1][2 * fp] + part[2][2 * fp] + part[3][2 * fp];
        float s1 = part[0][2 * fp + 1] + part[1][2 * fp + 1] + part[2][2 * fp + 1] + part[3][2 * fp + 1];
        float c = (float)(hi - lo);
        float d = c > 1.0f ? c : 1.0f;
        out[g * HIDDEN + 2 * fp]     = s0 / d;
        out[g * HIDDEN + 2 * fp + 1] = s1 / d;
    }
}

// ===========================================================================
extern "C" void kernel_launch(void* const* d_in, const int* in_sizes, int n_in,
                              void* d_out, int out_size, void* d_ws, size_t ws_size,
                              hipStream_t stream)
{
    const float* x   = (const float*)d_in[0];      // [N, 64]
    const int*   ei  = (const int*)d_in[1];        // [2, E]
    const float* ea  = (const float*)d_in[2];      // [E, 8]
    const int*   bat = (const int*)d_in[3];        // [N]
    const float* W1  = (const float*)d_in[4];
    const float* b1  = (const float*)d_in[5];
    const float* We1 = (const float*)d_in[6];
    const float* be1 = (const float*)d_in[7];
    const float* W2  = (const float*)d_in[8];
    const float* b2  = (const float*)d_in[9];
    const float* We2 = (const float*)d_in[10];
    const float* be2 = (const float*)d_in[11];
    const float* W3  = (const float*)d_in[12];
    const float* b3  = (const float*)d_in[13];
    const float* We3 = (const float*)d_in[14];
    const float* be3 = (const float*)d_in[15];
    float* out = (float*)d_out;

    const int* src = ei;
    const int* dst = ei + N_EDGES;

    // ---------------- workspace layout ----------------
    int* deg       = (int*)d_ws;                             // [N]
    int* rowptr    = deg + N_NODES;                          // [N]
    int* pos       = rowptr + N_NODES;                       // [N]
    int* src_s     = pos + N_NODES;                          // [E]
    int* blockSums = src_s + N_EDGES;                        // [128]
    __half* ea16   = (__half*)(blockSums + 128);             // [E, 8] fp16
    __half* xs     = ea16 + (size_t)N_EDGES * EDGE_DIM;      // [N,128] fp16
    __half* h3h    = xs + (size_t)N_NODES * HIDDEN;          // [N,128] fp16 (layer-3 out)
    unsigned char* xh8  = (unsigned char*)(h3h + (size_t)N_NODES * HIDDEN); // [N,64] fp8
    unsigned char* h1_8 = xh8 + (size_t)N_NODES * IN_CH;     // [N,128] fp8
    unsigned char* h2_8 = h1_8 + (size_t)N_NODES * HIDDEN;   // [N,128] fp8
    _Float16* Wt1  = (_Float16*)(h2_8 + (size_t)N_NODES * HIDDEN); // [128,64]
    _Float16* Wt2  = Wt1 + 128 * IN_CH;                      // [128,128]
    _Float16* Wt3  = Wt2 + 128 * HIDDEN;                     // [128,128]

    const int BLK = 256;
    const int NB_E = (N_EDGES + BLK - 1) / BLK;
    const int NB_N = (N_NODES + BLK - 1) / BLK;
    const int SCAN_B = (N_NODES + 511) / 512;    // 98
    const int MFMA_B = (N_NODES + 127) / 128;    // 391
    const int WAVE4_B = (N_NODES + 3) / 4;       // 12500 (4 waves/block, 1 node/wave)
    const int CVT_ELEMS = XH_ELEMS + 128 * IN_CH + 2 * 128 * HIDDEN;

    // ---------------- CSR build (sortless, record scatter) ----------------
    (void)hipMemsetAsync(deg, 0, N_NODES * sizeof(int), stream);
    hist_kernel<<<NB_E, BLK, 0, stream>>>(dst, deg, N_EDGES);
    scan1_kernel<<<SCAN_B, 256, 0, stream>>>(deg, pos, blockSums, N_NODES);
    scan2_kernel<<<1, 128, 0, stream>>>(blockSums, SCAN_B);
    scan3_kernel<<<NB_N, BLK, 0, stream>>>(pos, deg, blockSums, rowptr, pos, N_NODES);
    for (int pass = 0; pass < NPASS; ++pass) {
        scatter_rec_kernel<<<NB_E, BLK, 0, stream>>>(
            dst, src, ea, pos, src_s, ea16, pass * PASS_W, N_EDGES);
    }
    cvt_all_kernel<<<(CVT_ELEMS + BLK - 1) / BLK, BLK, 0, stream>>>(
        x, xh8, W1, W2, W3, Wt1, Wt2, Wt3);

    // ---------------- layer 1 (64 -> 128), fp8 out ----------------
    gather_xs64_kernel<<<WAVE4_B, BLK, 0, stream>>>(
        xh8, src_s, ea16, rowptr, deg, We1, be1, xs, N_NODES);
    node_mfma_kernel<IN_CH, true><<<MFMA_B, 256, 0, stream>>>(
        (const _Float16*)xs, Wt1, b1, nullptr, h1_8, N_NODES);

    // ---------------- layer 2 (128 -> 128), fp8 out ----------------
    gather_xs128_kernel<<<WAVE4_B, BLK, 0, stream>>>(
        h1_8, src_s, ea16, rowptr, deg, We2, be2, xs, N_NODES);
    node_mfma_kernel<HIDDEN, true><<<MFMA_B, 256, 0, stream>>>(
        (const _Float16*)xs, Wt2, b2, nullptr, h2_8, N_NODES);

    // ---------------- layer 3 (128 -> 128), fp16 out ----------------
    gather_xs128_kernel<<<WAVE4_B, BLK, 0, stream>>>(
        h2_8, src_s, ea16, rowptr, deg, We3, be3, xs, N_NODES);
    node_mfma_kernel<HIDDEN, false><<<MFMA_B, 256, 0, stream>>>(
        (const _Float16*)xs, Wt3, b3, (_Float16*)h3h, nullptr, N_NODES);

    // ---------------- global mean pool ----------------
    pool_kernel<<<NUM_GRAPHS, 256, 0, stream>>>(h3h, bat, out, N_NODES);
}